// Round 1
// 118.149 us; speedup vs baseline: 1.0033x; 1.0033x over previous
//
#include <hip/hip_runtime.h>
#include <cstdint>

// Problem constants: B=32, T=D=256, rows R = B*T = 8192, K = 256.
#define R_TOT 8192
#define KD    256
#define SLOT  ((size_t)R_TOT * KD)            // bytes per fp8 image (2,097,152)
// ws layout (bytes):  total ~4.8 MB
#define IVN_OFF  0                            // 64 f32: 1/frobenius-norm [ten][j]
#define ICN_OFF  256                          // 2*8192 f32: 1/col-norm [ten][j][s]
#define CSQ_OFF  (ICN_OFF + 65536)            // 8 tc-partials x 2*8192 f32 = 512 KB
#define MATS_OFF (CSQ_OFF + 524288)           // 2 fp8 images (Vq, Aq), swizzled, 4 MB

typedef float f32x4 __attribute__((ext_vector_type(4)));
typedef int   i32x4 __attribute__((ext_vector_type(4)));
typedef int   i32x8 __attribute__((ext_vector_type(8)));   // 32 fp8 = one MX MFMA operand

__device__ __forceinline__ void glds16(const void* g, void* l){
  __builtin_amdgcn_global_load_lds((const __attribute__((address_space(1))) uint32_t*)g,
                                   (__attribute__((address_space(3))) uint32_t*)l, 16, 0, 0);
}

// Image layout (R11-verbatim): plain k-order rows (256 B per image row r), 16B
// chunk c (k in [c*16, c*16+16)) stored at 16B slot c ^ (r & 15). XOR swizzle
// keeps MFMA-layout ds_read_b128 conflict-free (verified R7-R11, 65k conflicts).
__global__ void cast_ns_k(const float* __restrict__ V, const float* __restrict__ A,
                          unsigned char* __restrict__ mats, float* __restrict__ csq){
  const int tc = blockIdx.x, j = blockIdx.y, ten = blockIdx.z;
  const int tid = threadIdx.x;
  const int g    = tid & 31;                 // d-chunk of 8 floats = 8 fp8 bytes
  const int tsub = tid >> 5;                 // 0..7
  const int c    = g >> 1;                   // 16B chunk index 0..15
  const int half = g & 1;                    // which 8B half of the chunk
  const float* X = (ten ? A : V) + (size_t)j * 65536;
  unsigned char* M = mats + (size_t)ten * SLOT + (size_t)j * 65536;
  float cs[8];
  #pragma unroll
  for (int e = 0; e < 8; ++e) cs[e] = 0.f;
  #pragma unroll
  for (int tt = 0; tt < 4; ++tt){
    const int t = tc * 32 + tt * 8 + tsub;
    const float4 p0 = *(const float4*)(X + t * 256 + g * 8);
    const float4 p1 = *(const float4*)(X + t * 256 + g * 8 + 4);
    cs[0] += p0.x * p0.x; cs[1] += p0.y * p0.y; cs[2] += p0.z * p0.z; cs[3] += p0.w * p0.w;
    cs[4] += p1.x * p1.x; cs[5] += p1.y * p1.y; cs[6] += p1.z * p1.z; cs[7] += p1.w * p1.w;
    int d0 = __builtin_amdgcn_cvt_pk_fp8_f32(p0.x, p0.y, 0, false);
    d0     = __builtin_amdgcn_cvt_pk_fp8_f32(p0.z, p0.w, d0, true);
    int d1 = __builtin_amdgcn_cvt_pk_fp8_f32(p1.x, p1.y, 0, false);
    d1     = __builtin_amdgcn_cvt_pk_fp8_f32(p1.z, p1.w, d1, true);
    int2 o; o.x = d0; o.y = d1;
    *(int2*)(M + (size_t)t * 256 + (((c ^ (t & 15)) << 4) | (half << 3))) = o;
  }
  __shared__ float red[8][256];
  #pragma unroll
  for (int e = 0; e < 8; ++e) red[tsub][g * 8 + e] = cs[e];
  __syncthreads();
  float s = 0.f;
  #pragma unroll
  for (int gg = 0; gg < 8; ++gg) s += red[gg][tid];
  csq[(size_t)((tc * 2 + ten) * 32 + j) * 256 + tid] = s;
}

// Finish norms: sum 8 tc-partials; icn = rsqrt, ivn = rsqrt of row-sum. Grid (32, 2).
__global__ void nreduce_k(const float* __restrict__ csq, float* __restrict__ ivn,
                          float* __restrict__ icn){
  const int j = blockIdx.x, ten = blockIdx.y, s = threadIdx.x;
  float c = 0.f;
  #pragma unroll
  for (int tc = 0; tc < 8; ++tc)
    c += csq[(size_t)((tc * 2 + ten) * 32 + j) * 256 + s];
  icn[ten * 8192 + j * 256 + s] = rsqrtf(c + 1e-18f);
  __shared__ float red[256];
  red[s] = c; __syncthreads();
  for (int off = 128; off > 0; off >>= 1){
    if (s < off) red[s] += red[s + off];
    __syncthreads();
  }
  if (s == 0) ivn[ten * 32 + j] = rsqrtf(red[0] + 1e-18f);
}

// v14 = v13 + full 3-stage software pipeline per wave:
//   stage G: glds prefetch for x+1 (counted vmcnt(4), never 0 mid-loop)
//   stage L: ds_read b(x) into regs (issued BEFORE MFMAs that consume b(x-0's
//            already-in-register copy) -> lgkm latency hides under compute)
//   stage C: MFMA S(x); exp/acc consumes S(x-1) (S double-buffered) -> exp
//            never waits on a fresh MFMA.
// S zero-init via hoisted zero C operand (no per-iter v_movs). sched_barrier(0)
// after every lgkm wait (compiler may hoist reg-only MFMA past inline-asm
// waitcnt otherwise). s_setprio(1) around the compute cluster.
// Register cost ~160 VGPR -> __launch_bounds__(256,2): 2 waves/SIMD. Deliberate:
// pipelined waves need ILP not TLP; MFMA-pipe floor is occupancy-independent.
// Math is bit-identical to v13 (same ops, same j order).
__global__ __launch_bounds__(256, 2) void gemm_both_k(const unsigned char* __restrict__ mats,
                                                      const float* __restrict__ ivn,
                                                      const float* __restrict__ icn,
                                                      float* __restrict__ out){
  __shared__ __align__(16) char smem[40960];  // [0,32K): 4 waves x 2 x 4KB dbuf; [32K,40K): csc
  const int tid  = threadIdx.x;
  const int lane = tid & 63;
  const int w    = tid >> 6;
  const int dir  = w >> 1;              // waves 0,1 -> dir0; 2,3 -> dir1
  const int wn   = (w & 1) * 16;        // wave col slice in 32-col block tile
  const int lm   = lane & 15;
  const int kh   = lane >> 4;           // 0..3 (k-quad: k in [kh*32, kh*32+32) per K-half)
  const int s0   = blockIdx.x * 32;
  const int rb   = blockIdx.y;
  const int r0   = rb * 64;
  const int ib   = rb >> 2;             // batch index of this row tile (excluded diagonal)

  // dir0: rows Vq (scale 1/|V_i|F), cols Aq (scale 1/colnorm A); dir1 swapped.
  const unsigned char* rowmat = mats + (size_t)dir * SLOT;
  const unsigned char* colmat = mats + (size_t)(1 - dir) * SLOT;
  const float sivn = ivn[dir * 32 + ib] * 1.44269504088896340736f;  // * log2(e)

  char* wbase = smem + w * 8192;                       // wave-private dbuf (2 x 4KB)
  float* cscw = (float*)(smem + 32768) + w * 512;      // wave-private csc table
  const int lo16 = lane * 16;
  const unsigned char* colbase = colmat + (size_t)(s0 + wn) * 256;

  // glds prefetch for column-tile index x (x in [0,31), j = x + (x>=ib)).
  auto issue = [&](int x){
    const int j = x + (x >= ib ? 1 : 0);
    const unsigned char* src = colbase + (size_t)j * 65536;
    char* dst = wbase + ((x & 1) << 12);
    #pragma unroll
    for (int c = 0; c < 4; ++c)
      glds16(src + c * 1024 + lo16, dst + c * 1024 + lo16);
  };

  issue(0);   // start DMA of x=0 before anything else

  // Per-wave csc table: csc[j][lm] = sivn * icn_col[j*256 + lm], all 32 j.
  {
    const float* ibase = icn + (size_t)(1 - dir) * 8192 + s0 + wn;
    #pragma unroll
    for (int jx = 0; jx < 8; ++jx){
      const int j = kh * 8 + jx;
      cscw[j * 16 + lm] = sivn * ibase[j * 256 + lm];
    }
  }

  // A-fragments: all 64 rows of this wave's dir; K-half t, 16B unit u at slot
  // (t*8 + kh*2 + u) ^ lm. 64 VGPRs, loop-invariant.
  i32x8 afr[4][2];                      // [mi][K-half]
  #pragma unroll
  for (int mi = 0; mi < 4; ++mi){
    const unsigned char* rp = rowmat + (size_t)(r0 + mi * 16 + lm) * 256;
    #pragma unroll
    for (int t = 0; t < 2; ++t){
      i32x4 lo = *(const i32x4*)(rp + ((((t << 3) | (kh << 1) | 0) ^ lm) << 4));
      i32x4 hi = *(const i32x4*)(rp + ((((t << 3) | (kh << 1) | 1) ^ lm) << 4));
      afr[mi][t] = i32x8{lo.x, lo.y, lo.z, lo.w, hi.x, hi.y, hi.z, hi.w};
    }
  }
  #pragma unroll
  for (int mi = 0; mi < 4; ++mi)
    #pragma unroll
    for (int t = 0; t < 2; ++t)
      asm volatile("" : "+v"(afr[mi][t]));

  // j-invariant ds_read offsets (row-in-slice == lm).
  int ad[2][2];                         // [K-half][16B unit]
  #pragma unroll
  for (int t = 0; t < 2; ++t)
    #pragma unroll
    for (int u = 0; u < 2; ++u)
      ad[t][u] = lm * 256 + ((((t << 3) | (kh << 1) | u) ^ lm) << 4);

  f32x4 acc[4];
  #pragma unroll
  for (int mi = 0; mi < 4; ++mi)
    acc[mi] = f32x4{0.f, 0.f, 0.f, 0.f};
  const f32x4 fz = {0.f, 0.f, 0.f, 0.f};   // hoisted zero C-operand for MFMA t=0

  i32x8 bA[2], bB[2];                   // b fragments, double-buffered (named, no runtime idx)
  f32x4 SA[4], SB[4];                   // S double-buffer: exp consumes last iter's S
  float cscA, cscB;

#define DSREAD(BX, CX, x_) do{                                                  \
    const char* rbuf_ = wbase + (((x_) & 1) << 12);                             \
    i32x4 lo0_ = *(const i32x4*)(rbuf_ + ad[0][0]);                             \
    i32x4 hi0_ = *(const i32x4*)(rbuf_ + ad[0][1]);                             \
    i32x4 lo1_ = *(const i32x4*)(rbuf_ + ad[1][0]);                             \
    i32x4 hi1_ = *(const i32x4*)(rbuf_ + ad[1][1]);                             \
    BX[0] = i32x8{lo0_.x, lo0_.y, lo0_.z, lo0_.w, hi0_.x, hi0_.y, hi0_.z, hi0_.w}; \
    BX[1] = i32x8{lo1_.x, lo1_.y, lo1_.z, lo1_.w, hi1_.x, hi1_.y, hi1_.z, hi1_.w}; \
    const int j_ = (x_) + ((x_) >= ib ? 1 : 0);                                 \
    CX = cscw[j_ * 16 + lm];                                                    \
  }while(0)

#define MFMA8(SX, BX) do{                                                       \
    SX[0] = __builtin_amdgcn_mfma_scale_f32_16x16x128_f8f6f4(afr[0][0], BX[0], fz,    0, 0, 0, 127, 0, 127); \
    SX[1] = __builtin_amdgcn_mfma_scale_f32_16x16x128_f8f6f4(afr[1][0], BX[0], fz,    0, 0, 0, 127, 0, 127); \
    SX[2] = __builtin_amdgcn_mfma_scale_f32_16x16x128_f8f6f4(afr[2][0], BX[0], fz,    0, 0, 0, 127, 0, 127); \
    SX[3] = __builtin_amdgcn_mfma_scale_f32_16x16x128_f8f6f4(afr[3][0], BX[0], fz,    0, 0, 0, 127, 0, 127); \
    SX[0] = __builtin_amdgcn_mfma_scale_f32_16x16x128_f8f6f4(afr[0][1], BX[1], SX[0], 0, 0, 0, 127, 0, 127); \
    SX[1] = __builtin_amdgcn_mfma_scale_f32_16x16x128_f8f6f4(afr[1][1], BX[1], SX[1], 0, 0, 0, 127, 0, 127); \
    SX[2] = __builtin_amdgcn_mfma_scale_f32_16x16x128_f8f6f4(afr[2][1], BX[1], SX[2], 0, 0, 0, 127, 0, 127); \
    SX[3] = __builtin_amdgcn_mfma_scale_f32_16x16x128_f8f6f4(afr[3][1], BX[1], SX[3], 0, 0, 0, 127, 0, 127); \
  }while(0)

#define EXPACC(SY, CY) do{                                                      \
    _Pragma("unroll")                                                           \
    for (int mi_ = 0; mi_ < 4; ++mi_){                                          \
      _Pragma("unroll")                                                         \
      for (int r_ = 0; r_ < 4; ++r_)                                            \
        acc[mi_][r_] += __builtin_amdgcn_exp2f(SY[mi_][r_] * CY);               \
    }                                                                           \
  }while(0)

// One pipeline step for tile x: prefetch x+1 (if PF), wait for x's DMA
// (vmcnt(4): the 4 just-issued stay in flight), ds_read b(x)+csc(x), then
// compute S(x) and exp/acc the PREVIOUS tile's S. PF is a literal 0/1.
#define STEP(x_, BX, SX, CX, SY, CY, PF) do{                                    \
    if (PF) issue((x_) + 1);                                                    \
    if (PF) asm volatile("s_waitcnt vmcnt(4)" ::: "memory");                    \
    else    asm volatile("s_waitcnt vmcnt(0)" ::: "memory");                    \
    DSREAD(BX, CX, x_);                                                         \
    asm volatile("s_waitcnt lgkmcnt(0)" ::: "memory");                          \
    __builtin_amdgcn_sched_barrier(0);                                          \
    __builtin_amdgcn_s_setprio(1);                                              \
    MFMA8(SX, BX);                                                              \
    EXPACC(SY, CY);                                                             \
    __builtin_amdgcn_s_setprio(0);                                              \
  }while(0)

  // ---- prologue: drain everything (preload x=0 DMA, csc writes, afr loads) ----
  asm volatile("s_waitcnt vmcnt(0) lgkmcnt(0)" ::: "memory");
  __builtin_amdgcn_sched_barrier(0);
  DSREAD(bA, cscA, 0);                  // b(0) -> regs
  issue(1);                             // DMA x=1 into phase 1
  asm volatile("s_waitcnt lgkmcnt(0)" ::: "memory");
  __builtin_amdgcn_sched_barrier(0);
  __builtin_amdgcn_s_setprio(1);
  MFMA8(SA, bA);                        // S(0)
  __builtin_amdgcn_s_setprio(0);

  // ---- steady state: 31 tiles, odd->B, even->A ----
  #pragma unroll 1
  for (int it = 0; it < 14; ++it){
    STEP(2 * it + 1, bB, SB, cscB, SA, cscA, 1);
    STEP(2 * it + 2, bA, SA, cscA, SB, cscB, 1);
  }
  STEP(29, bB, SB, cscB, SA, cscA, 1);
  STEP(30, bA, SA, cscA, SB, cscB, 0);  // last tile: drain vmcnt(0), no prefetch
  EXPACC(SA, cscA);                     // flush S(30)

#undef STEP
#undef EXPACC
#undef MFMA8
#undef DSREAD

  // Epilogue: per-dir log1p into LDS ([2][64][36] f32 = 18KB), combine, coalesced store.
  // C/D layout: col = lane&15, row = (lane>>4)*4 + reg (shape-determined, incl. f8f6f4).
  __syncthreads();                      // all waves' loop LDS reads done (lgkm drained above)
  float* ebuf = (float*)smem;
  #pragma unroll
  for (int mi = 0; mi < 4; ++mi){
    const int n = wn + lm;
    #pragma unroll
    for (int r = 0; r < 4; ++r){
      const int m = mi * 16 + (kh << 2) + r;
      ebuf[(dir * 64 + m) * 36 + n] = __logf(1.f + acc[mi][r]);
    }
  }
  __syncthreads();
  #pragma unroll
  for (int p = 0; p < 2; ++p){
    const int i   = tid + p * 256;     // 0..511 (float4 units of the 64x32 tile)
    const int row = i >> 3;
    const int c4  = i & 7;
    const f32x4 e0 = *(const f32x4*)(&ebuf[row * 36 + c4 * 4]);
    const f32x4 e1 = *(const f32x4*)(&ebuf[(64 + row) * 36 + c4 * 4]);
    f32x4 o;
    #pragma unroll
    for (int e = 0; e < 4; ++e) o[e] = -(e0[e] + e1[e]);
    *(f32x4*)(&out[(size_t)(r0 + row) * 256 + s0 + c4 * 4]) = o;
  }
}

extern "C" void kernel_launch(void* const* d_in, const int* in_sizes, int n_in,
                              void* d_out, int out_size, void* d_ws, size_t ws_size,
                              hipStream_t stream){
  const float* V = (const float*)d_in[2];   // back_VF  (pre_VF/pre_AF unused by reference)
  const float* A = (const float*)d_in[3];   // back_AF
  float* out = (float*)d_out;
  float* ivn = (float*)((char*)d_ws + IVN_OFF);
  float* icn = (float*)((char*)d_ws + ICN_OFF);
  float* csq = (float*)((char*)d_ws + CSQ_OFF);
  unsigned char* mats = (unsigned char*)((char*)d_ws + MATS_OFF);

  cast_ns_k<<<dim3(8, 32, 2), 256, 0, stream>>>(V, A, mats, csq);
  nreduce_k<<<dim3(32, 2), 256, 0, stream>>>(csq, ivn, icn);
  gemm_both_k<<<dim3(8, 128), 256, 0, stream>>>(mats, ivn, icn, out);
}